// Round 6
// baseline (26.814 us; speedup 1.0000x reference)
//
#include <hip/hip_runtime.h>
#include <math.h>

// SegmentTreeAttention — MI355X (gfx950), round 6.
// B=16, S=8192, D=64, N=32, LEVELS=5. f32 in/out. valid_lens per-batch.
//
// vs round 5 (26.5us, latency-chain bound):
//  - Speculative dual-mid prefetch: mid(lev+1) = mid +/- (8>>lev), both
//    candidate Pk rows are read BEFORE cond resolves; next level selects
//    in registers -> LDS latency off the serial descent chain.
//  - Clamped-read identity: row min(mid,hnc) serves as both P[mid] and
//    the hiL fallback (all clamp-divergent cases are masked by ok/w=0),
//    removing the pkN register pair and 16 cndmask per level.
//  - q loads hoisted above LDS staging (global latency hidden there).
// Numerics bit-identical to passing rounds: IEEE-div sigmoid
// 1/(1+__expf(-s)), subtract-then-dot segments, DPP butterfly reduce,
// pow2 level scales, post-reduce zero-masking.

#define SEG_N   32
#define DIM     64
#define LEVELS  5
#define QPB     64      // queries per block
#define THREADS 256
#define PAD     68      // LDS row stride in dwords

#define DPP_QUAD_XOR1   0xB1    // quad_perm [1,0,3,2]
#define DPP_QUAD_XOR2   0x4E    // quad_perm [2,3,0,1]
#define DPP_ROW_HMIRROR 0x141   // row_half_mirror (lane p -> 7-p within 8)

template <int CTRL>
__device__ __forceinline__ float dpp_xadd(float v) {
    const int s = __builtin_amdgcn_update_dpp(0, __float_as_int(v), CTRL, 0xf, 0xf, true);
    return v + __int_as_float(s);
}

// 8-lane group sum, all lanes get the bit-identical total.
__device__ __forceinline__ float group8_sum(float v) {
    v = dpp_xadd<DPP_QUAD_XOR1>(v);
    v = dpp_xadd<DPP_QUAD_XOR2>(v);
    v = dpp_xadd<DPP_ROW_HMIRROR>(v);
    return v;
}

__device__ __forceinline__ float4 f4sub(const float4 a, const float4 b) {
    return make_float4(a.x - b.x, a.y - b.y, a.z - b.z, a.w - b.w);
}
__device__ __forceinline__ float4 sel4(bool c, const float4 a, const float4 b) {
    return make_float4(c ? a.x : b.x, c ? a.y : b.y, c ? a.z : b.z, c ? a.w : b.w);
}
__device__ __forceinline__ float dot4(const float4 a, const float4 b) {
    return a.x * b.x + a.y * b.y + a.z * b.z + a.w * b.w;
}
__device__ __forceinline__ void fma4(float4& acc, const float4 hi, const float4 lo, float w) {
    acc.x = fmaf(hi.x - lo.x, w, acc.x);
    acc.y = fmaf(hi.y - lo.y, w, acc.y);
    acc.z = fmaf(hi.z - lo.z, w, acc.z);
    acc.w = fmaf(hi.w - lo.w, w, acc.w);
}

__global__ __launch_bounds__(THREADS) void segtree_attn_kernel(
    const float* __restrict__ q,
    const float* __restrict__ keys,
    const float* __restrict__ values,
    const int*   __restrict__ vlen,
    float*       __restrict__ out,
    int S)
{
    __shared__ float Pk[SEG_N * PAD];
    __shared__ float Pv[SEG_N * PAD];

    const int b = blockIdx.y;
    const int t = threadIdx.x;
    const int g = t >> 3;           // query group within block (0..31)
    const int u = t & 7;            // lane within group
    const int c = u * 8;            // column base (2x float4)

    const int sA = blockIdx.x * QPB + g;
    const int sB = sA + 32;

    // ---- q loads hoisted: latency hides under staging + barrier ----
    const float* qpA = q + ((size_t)b * S + sA) * DIM + c;
    const float* qpB = q + ((size_t)b * S + sB) * DIM + c;
    const float4 qA0 = *(const float4*)qpA;
    const float4 qA1 = *(const float4*)(qpA + 4);
    const float4 qB0 = *(const float4*)qpB;
    const float4 qB1 = *(const float4*)(qpB + 4);

    // ---- Stage prefix sums into LDS: P[0]=0, P[m]=sum_{l=1..m} x[l] ----
    if (t < 2 * DIM) {
        const int col = t & (DIM - 1);
        const float* src = ((t < DIM) ? keys : values) + (size_t)b * SEG_N * DIM + col;
        float* dst = (t < DIM) ? Pk : Pv;
        float acc = 0.0f;
        dst[col] = 0.0f;
        #pragma unroll
        for (int row = 1; row < SEG_N; ++row) {
            acc += src[row * DIM];
            dst[row * PAD + col] = acc;
        }
    }
    const int n = vlen[b];          // block-uniform (valid_lens is [B])
    __syncthreads();

    const int hnc = max(min(n - 1, SEG_N - 1), 0);
    const float scale[LEVELS] = {0.0625f, 0.125f, 0.25f, 0.5f, 1.0f};

    // ---- prologue: level-0 mid row (16, shared) + hnc row ----
    const int cm16 = min(16, hnc);
    float4 pkM_A0 = *(const float4*)&Pk[cm16 * PAD + c];
    float4 pkM_A1 = *(const float4*)&Pk[cm16 * PAD + c + 4];
    float4 pkM_B0 = pkM_A0, pkM_B1 = pkM_A1;
    const float4 pkRi0 = *(const float4*)&Pk[hnc * PAD + c];
    const float4 pkRi1 = *(const float4*)&Pk[hnc * PAD + c + 4];

    float4 pkR_A0 = pkRi0, pkR_A1 = pkRi1;
    float4 pkR_B0 = pkRi0, pkR_B1 = pkRi1;
    float4 pkA_A0 = make_float4(0.f,0.f,0.f,0.f), pkA_A1 = make_float4(0.f,0.f,0.f,0.f);
    float4 pkA_B0 = make_float4(0.f,0.f,0.f,0.f), pkA_B1 = make_float4(0.f,0.f,0.f,0.f);

    int midA = 16, midB = 16;
    int lA = 1, rA = SEG_N, rowA_A = 0, rowR_A = hnc;
    int lB = 1, rB = SEG_N, rowA_B = 0, rowR_B = hnc;

    float wA[LEVELS], wB[LEVELS];
    int   rows[LEVELS];             // hiA | loA<<8 | hiB<<16 | loB<<24

    #pragma unroll
    for (int lev = 0; lev < LEVELS; ++lev) {
        const int step = 8 >> lev;
        const int cmA = min(midA, hnc);     // clamped current row index
        const int cmB = min(midB, hnc);

        // ---- speculative prefetch of BOTH next-mid candidate rows ----
        float4 sLoA0, sLoA1, sHiA0, sHiA1, sLoB0, sLoB1, sHiB0, sHiB1;
        int midLoA = 0, midHiA = 0, midLoB = 0, midHiB = 0;
        if (lev < LEVELS - 1) {
            midLoA = midA - step; midHiA = midA + step;
            midLoB = midB - step; midHiB = midB + step;
            const int rLoA = min(midLoA, hnc), rHiA = min(midHiA, hnc);
            const int rLoB = min(midLoB, hnc), rHiB = min(midHiB, hnc);
            sLoA0 = *(const float4*)&Pk[rLoA * PAD + c];
            sLoA1 = *(const float4*)&Pk[rLoA * PAD + c + 4];
            sHiA0 = *(const float4*)&Pk[rHiA * PAD + c];
            sHiA1 = *(const float4*)&Pk[rHiA * PAD + c + 4];
            sLoB0 = *(const float4*)&Pk[rLoB * PAD + c];
            sLoB1 = *(const float4*)&Pk[rLoB * PAD + c + 4];
            sHiB0 = *(const float4*)&Pk[rHiB * PAD + c];
            sHiB1 = *(const float4*)&Pk[rHiB * PAD + c + 4];
        }

        // subtract-then-dot (matches reference rounding structure);
        // pkM holds the CLAMPED row value (divergence from unclamped is
        // provably masked by okL/okR/w=0 in every reachable case).
        float dLA = dot4(qA0, f4sub(pkM_A0, pkA_A0)) + dot4(qA1, f4sub(pkM_A1, pkA_A1));
        float dRA = dot4(qA0, f4sub(pkR_A0, pkM_A0)) + dot4(qA1, f4sub(pkR_A1, pkM_A1));
        float dLB = dot4(qB0, f4sub(pkM_B0, pkA_B0)) + dot4(qB1, f4sub(pkM_B1, pkA_B1));
        float dRB = dot4(qB0, f4sub(pkR_B0, pkM_B0)) + dot4(qB1, f4sub(pkR_B1, pkM_B1));

        dLA = group8_sum(dLA);
        dRA = group8_sum(dRA);
        dLB = group8_sum(dLB);
        dRB = group8_sum(dRB);

        const bool okLA = (min(midA, n - 1) >= lA);
        const bool okRA = (min(rA,   n - 1) >= midA + 1);
        const bool okLB = (min(midB, n - 1) >= lB);
        const bool okRB = (min(rB,   n - 1) >= midB + 1);

        const float sLA = okLA ? dLA : 0.0f;
        const float sRA = okRA ? dRA : 0.0f;
        const float sLB = okLB ? dLB : 0.0f;
        const float sRB = okRB ? dRB : 0.0f;

        // exact formula from the passing rounds (IEEE div)
        const float lsA = 1.0f / (1.0f + __expf(-sLA));
        const float rsA = 1.0f / (1.0f + __expf(-sRA));
        const float lsB = 1.0f / (1.0f + __expf(-sLB));
        const float rsB = 1.0f / (1.0f + __expf(-sRB));

        const bool condA = (lsA >= rsA);
        const bool condB = (lsB >= rsB);

        const bool  okselA = condA ? okRA : okLA;
        const bool  okselB = condB ? okRB : okLB;
        const float wselA  = condA ? rsA : lsA;
        const float wselB  = condB ? rsB : lsB;
        wA[lev] = okselA ? (wselA * scale[lev]) : 0.0f;   // pow2 scale: exact
        wB[lev] = okselB ? (wselB * scale[lev]) : 0.0f;

        const int hiA = condA ? rowR_A : cmA;
        const int loA = condA ? midA   : rowA_A;
        const int hiB = condB ? rowR_B : cmB;
        const int loB = condB ? midB   : rowA_B;
        rows[lev] = hiA | (loA << 8) | (hiB << 16) | (loB << 24);

        if (condA) {
            rA = midA; rowR_A = cmA;
            pkR_A0 = pkM_A0; pkR_A1 = pkM_A1;
        } else {
            lA = midA + 1; rowA_A = midA;
            pkA_A0 = pkM_A0; pkA_A1 = pkM_A1;
        }
        if (condB) {
            rB = midB; rowR_B = cmB;
            pkR_B0 = pkM_B0; pkR_B1 = pkM_B1;
        } else {
            lB = midB + 1; rowA_B = midB;
            pkA_B0 = pkM_B0; pkA_B1 = pkM_B1;
        }

        if (lev < LEVELS - 1) {
            midA = condA ? midLoA : midHiA;
            midB = condB ? midLoB : midHiB;
            pkM_A0 = sel4(condA, sLoA0, sHiA0);
            pkM_A1 = sel4(condA, sLoA1, sHiA1);
            pkM_B0 = sel4(condB, sLoB0, sHiB0);
            pkM_B1 = sel4(condB, sLoB1, sHiB1);
        }
    }

    // ---- deferred value gather: ans = sum_lev w * (Pv[hi] - Pv[lo]) ----
    float4 aA0 = make_float4(0.f,0.f,0.f,0.f), aA1 = make_float4(0.f,0.f,0.f,0.f);
    float4 aB0 = make_float4(0.f,0.f,0.f,0.f), aB1 = make_float4(0.f,0.f,0.f,0.f);
    #pragma unroll
    for (int lev = 0; lev < LEVELS; ++lev) {
        const int pk = rows[lev];
        const int hiAr = pk & 0xFF, loAr = (pk >> 8) & 0xFF;
        const int hiBr = (pk >> 16) & 0xFF, loBr = (pk >> 24) & 0xFF;
        const float4 hA0 = *(const float4*)&Pv[hiAr * PAD + c];
        const float4 hA1 = *(const float4*)&Pv[hiAr * PAD + c + 4];
        const float4 lA0 = *(const float4*)&Pv[loAr * PAD + c];
        const float4 lA1 = *(const float4*)&Pv[loAr * PAD + c + 4];
        fma4(aA0, hA0, lA0, wA[lev]);
        fma4(aA1, hA1, lA1, wA[lev]);
        const float4 hB0 = *(const float4*)&Pv[hiBr * PAD + c];
        const float4 hB1 = *(const float4*)&Pv[hiBr * PAD + c + 4];
        const float4 lB0 = *(const float4*)&Pv[loBr * PAD + c];
        const float4 lB1 = *(const float4*)&Pv[loBr * PAD + c + 4];
        fma4(aB0, hB0, lB0, wB[lev]);
        fma4(aB1, hB1, lB1, wB[lev]);
    }

    float* opA = out + ((size_t)b * S + sA) * DIM + c;
    float* opB = out + ((size_t)b * S + sB) * DIM + c;
    *(float4*)opA       = aA0;
    *(float4*)(opA + 4) = aA1;
    *(float4*)opB       = aB0;
    *(float4*)(opB + 4) = aB1;
}

extern "C" void kernel_launch(void* const* d_in, const int* in_sizes, int n_in,
                              void* d_out, int out_size, void* d_ws, size_t ws_size,
                              hipStream_t stream) {
    const float* q    = (const float*)d_in[0];
    const float* keys = (const float*)d_in[1];
    const float* vals = (const float*)d_in[2];
    const int*   vl   = (const int*)d_in[3];
    float* out = (float*)d_out;

    const int B = in_sizes[3];                 // 16
    const int S = in_sizes[0] / (B * DIM);     // 8192

    dim3 grid(S / QPB, B);
    segtree_attn_kernel<<<grid, THREADS, 0, stream>>>(q, keys, vals, vl, out, S);
}